// Round 5
// baseline (121.610 us; speedup 1.0000x reference)
//
#include <hip/hip_runtime.h>
#include <stdint.h>

// ---------------- problem constants ----------------
#define B_SZ 8192
#define LOG8 2.0794415416798357f   // -log(1/8)
#define NTILE 2080                 // 64*65/2 upper-triangular 128x128 tiles
#define NCHUNK 520                 // 4 tiles per block

typedef __attribute__((ext_vector_type(8))) short short8;
typedef __attribute__((ext_vector_type(4))) float floatx4;

__device__ inline unsigned short f2bf(float f) {
    unsigned int u = __float_as_uint(f);
    u = (u + 0x7FFFu + ((u >> 16) & 1u)) >> 16;   // RNE
    return (unsigned short)u;
}
__device__ inline float bf2f(unsigned short s) {
    return __uint_as_float(((unsigned int)s) << 16);
}
__device__ inline float wredf(float x) {
#pragma unroll
    for (int o = 32; o; o >>= 1) x += __shfl_down(x, o);
    return x;
}
__device__ inline int wredi(int x) {
#pragma unroll
    for (int o = 32; o; o >>= 1) x += __shfl_down(x, o);
    return x;
}

// ws layout:
//  nrm      bf16[8192*128]   @ 0        (2097152 B)
//  nlq      bf16[8192*8]     @ 2097152  (-(logp+log8), sign-flipped bf16)
//  pb       bf16[8192*8]     @ 2228224
//  aprime   f32[8192]        @ 2359296  (sum p~*lq~, fp32)
//  klslot   f32[520]         @ 2392064  (per-block, non-atomic)
//  cntslot  u32[520]         @ 2394144
//  prepslot f32[32*11]       @ 2396224  (task,eff,ent,cs[8] per routing block)

// ---------------- fused prep ----------------
__global__ void prep_all(const float* __restrict__ logits,
                         const int* __restrict__ targets,
                         const float* __restrict__ routing,
                         const float* __restrict__ emb,
                         unsigned short* __restrict__ nrm,
                         unsigned short* __restrict__ nlq,
                         unsigned short* __restrict__ pb,
                         float* __restrict__ aprime,
                         float* __restrict__ prepslot) {
    __shared__ float pred[4][11];
    const int bid = blockIdx.x;
    const int lane = threadIdx.x & 63;
    const int wave = threadIdx.x >> 6;

    if (bid < 2048) {
        // ---- embedding normalize -> bf16 (wave per row) ----
        int row = (bid << 2) + wave;
        const float2* e2 = (const float2*)(emb + (size_t)row * 128);
        float2 v = e2[lane];
        float ss = v.x * v.x + v.y * v.y;
        ss = wredf(ss);
        ss = __shfl(ss, 0);
        float inv = rsqrtf(ss);
        ushort2 o;
        o.x = f2bf(v.x * inv);
        o.y = f2bf(v.y * inv);
        ((ushort2*)(nrm + (size_t)row * 128))[lane] = o;
        return;
    }

    // ---- per-row routing prep ----
    int row = ((bid - 2048) << 8) + threadIdx.x;

    const float4* r4 = (const float4*)(routing + (size_t)row * 8);
    float4 va = r4[0], vb = r4[1];
    float v[8] = {va.x, va.y, va.z, va.w, vb.x, vb.y, vb.z, vb.w};

    float mx = v[0];
#pragma unroll
    for (int e = 1; e < 8; ++e) mx = fmaxf(mx, v[e]);
    float ex[8], s = 0.f;
#pragma unroll
    for (int e = 0; e < 8; ++e) { ex[e] = expf(v[e] - mx); s += ex[e]; }
    float ls = logf(s);
    float inv_s = 1.f / s;

    union { unsigned short u[8]; uint4 q; } lu, pu;
    float ap = 0.f;
#pragma unroll
    for (int e = 0; e < 8; ++e) {
        unsigned short pe = f2bf(ex[e] * inv_s);
        unsigned short le = f2bf(v[e] - mx - ls + LOG8);
        pu.u[e] = pe;
        lu.u[e] = le ^ 0x8000;             // store -lq (exact sign flip)
        ap += bf2f(pe) * bf2f(le);
    }
    ((uint4*)nlq)[row] = lu.q;
    ((uint4*)pb)[row] = pu.q;
    aprime[row] = ap;

    float eff = 0.f, ent = 0.f;
#pragma unroll
    for (int e = 0; e < 8; ++e) {
        if (v[e] < 0.1f) eff += v[e];
        ent += v[e] * logf(v[e] + 1e-8f);
    }

    const float* lg = logits + (size_t)row * 3;
    float a0 = lg[0], a1 = lg[1], a2 = lg[2];
    float mm = fmaxf(a0, fmaxf(a1, a2));
    float lse = mm + logf(expf(a0 - mm) + expf(a1 - mm) + expf(a2 - mm));
    int tg = targets[row];
    float tv = (tg == 0) ? a0 : ((tg == 1) ? a1 : a2);
    float task = lse - tv;

    task = wredf(task);
    eff = wredf(eff);
    ent = wredf(ent);
    float cs[8];
#pragma unroll
    for (int e = 0; e < 8; ++e) cs[e] = wredf(v[e]);

    if (lane == 0) {
        pred[wave][0] = task;
        pred[wave][1] = eff;
        pred[wave][2] = ent;
#pragma unroll
        for (int e = 0; e < 8; ++e) pred[wave][3 + e] = cs[e];
    }
    __syncthreads();
    if (threadIdx.x < 11) {
        prepslot[(bid - 2048) * 11 + threadIdx.x] =
            pred[0][threadIdx.x] + pred[1][threadIdx.x] +
            pred[2][threadIdx.x] + pred[3][threadIdx.x];
    }
}

// ---------------- main: chunked symmetric sim-mask + KL ----------------
// 520 blocks x 4 consecutive triangular tiles; A staged per-chunk,
// B register-prefetch pipelined; kl = MFMA(ap_i + ap_j - cross) directly.
__global__ __launch_bounds__(512, 4) void tile_sym(
    const unsigned short* __restrict__ nrm,
    const unsigned short* __restrict__ nlq,
    const unsigned short* __restrict__ pb,
    const float* __restrict__ aprime,
    float* __restrict__ klslot,
    unsigned int* __restrict__ cntslot) {
    __shared__ uint4 sh[2][128][16];   // 64 KB: [0]=A panel, [1]=B panel

    const int t = threadIdx.x;
    const int L0 = blockIdx.x << 2;

    // triangular decode of first tile: bi <= bj
    int bi = (int)((129.0f - sqrtf((float)(16641 - 8 * L0))) * 0.5f);
    int T = bi * 64 - ((bi * (bi - 1)) >> 1);
    while (L0 < T) { --bi; T = bi * 64 - ((bi * (bi - 1)) >> 1); }
    while (L0 >= T + (64 - bi)) { T += 64 - bi; ++bi; }
    int bj = bi + (L0 - T);

    const uint4* n4 = (const uint4*)nrm;
    const int wave = t >> 6, lane = t & 63;
    const int wr = wave >> 2, wc = wave & 3;   // 2 x 4 wave grid
    const int m = lane & 15, q = lane >> 4;
    const short8 zero8 = (short8){0, 0, 0, 0, 0, 0, 0, 0};

    float klLocal = 0.f;
    int cntLocal = 0;
    int prev_bi = -1;
    uint4 bpre[4];

#pragma unroll 1
    for (int tt = 0; tt < 4; ++tt) {
        const bool diag = (bi == bj);
        const int iBase = bi << 7, jBase = bj << 7;

        if (tt == 0) {
            // stage A and B panels
#pragma unroll
            for (int it = 0; it < 4; ++it) {
                int cc = t + (it << 9);
                int row = cc >> 4, g = cc & 15;
                int gp = g ^ (row & 15);
                sh[0][row][gp] = n4[((size_t)(iBase + row) << 4) + g];
                sh[1][row][gp] = n4[((size_t)(jBase + row) << 4) + g];
            }
        } else {
            __syncthreads();               // everyone done with previous tile
#pragma unroll
            for (int it = 0; it < 4; ++it) {
                int cc = t + (it << 9);
                int row = cc >> 4, g = cc & 15;
                sh[1][row][g ^ (row & 15)] = bpre[it];
            }
            if (bi != prev_bi) {           // rare: chunk crossed a row boundary
#pragma unroll
                for (int it = 0; it < 4; ++it) {
                    int cc = t + (it << 9);
                    int row = cc >> 4, g = cc & 15;
                    sh[0][row][g ^ (row & 15)] = n4[((size_t)(iBase + row) << 4) + g];
                }
            }
        }
        __syncthreads();                   // LDS ready

        // next tile coords + B prefetch (overlaps this tile's compute)
        int nbi = bi, nbj = bj + 1;
        if (nbj == 64) { nbi = bi + 1; nbj = nbi; }
        if (tt < 3) {
#pragma unroll
            for (int it = 0; it < 4; ++it) {
                int cc = t + (it << 9);
                int row = cc >> 4, g = cc & 15;
                bpre[it] = n4[((size_t)((nbj << 7) + row) << 4) + g];
            }
        }

        // cross fragments: kl[i,j] = ap_i + ap_j - lq_i.p_j - p_i.lq_j
        //  A: q0 = -lq_i, q1 = p_i (0 on diag), q2 = {bf16(ap_i) (0 on diag), 1}
        //  B: q0 = p_j,   q1 = -lq_j,           q2 = {1, bf16(ap_j)}
        short8 crA[4], crB[2];
#pragma unroll
        for (int a = 0; a < 4; ++a) {
            int ri = iBase + (wr << 6) + (a << 4) + m;
            short8 v = zero8;
            if (q == 0) v = *(const short8*)&nlq[(size_t)ri << 3];
            else if (q == 1) { if (!diag) v = *(const short8*)&pb[(size_t)ri << 3]; }
            else if (q == 2) {
                v[1] = (short)0x3F80;
                if (!diag) v[0] = (short)f2bf(aprime[ri]);
            }
            crA[a] = v;
        }
#pragma unroll
        for (int b = 0; b < 2; ++b) {
            int cj = jBase + (wc << 5) + (b << 4) + m;
            short8 v = zero8;
            if (q == 0) v = *(const short8*)&pb[(size_t)cj << 3];
            else if (q == 1) v = *(const short8*)&nlq[(size_t)cj << 3];
            else if (q == 2) {
                v[0] = (short)0x3F80;
                v[1] = (short)f2bf(aprime[cj]);
            }
            crB[b] = v;
        }

        const unsigned short* Ab = (const unsigned short*)&sh[0][0][0];
        const unsigned short* Bb = (const unsigned short*)&sh[1][0][0];

        floatx4 simacc[4][2];
#pragma unroll
        for (int a = 0; a < 4; ++a)
#pragma unroll
            for (int b = 0; b < 2; ++b) simacc[a][b] = (floatx4){0.f, 0.f, 0.f, 0.f};

        // sim = A . B^T over K=128
#pragma unroll
        for (int ks = 0; ks < 4; ++ks) {
            const int g = (ks << 2) + q;
            short8 af[4], bfr[2];
#pragma unroll
            for (int a = 0; a < 4; ++a) {
                int ra = (wr << 6) + (a << 4) + m;
                af[a] = *(const short8*)&Ab[(ra << 7) + ((g ^ m) << 3)];
            }
#pragma unroll
            for (int b = 0; b < 2; ++b) {
                int rb = (wc << 5) + (b << 4) + m;
                bfr[b] = *(const short8*)&Bb[(rb << 7) + ((g ^ m) << 3)];
            }
#pragma unroll
            for (int a = 0; a < 4; ++a)
#pragma unroll
                for (int b = 0; b < 2; ++b)
                    simacc[a][b] = __builtin_amdgcn_mfma_f32_16x16x32_bf16(
                        af[a], bfr[b], simacc[a][b], 0, 0, 0);
        }

        // epilogue: kl via one MFMA, then masked accumulate
#pragma unroll
        for (int a = 0; a < 4; ++a) {
            const int gRow0 = iBase + (wr << 6) + (a << 4) + (q << 2);
#pragma unroll
            for (int b = 0; b < 2; ++b) {
                const int gCol = jBase + (wc << 5) + (b << 4) + m;
                floatx4 cr = __builtin_amdgcn_mfma_f32_16x16x32_bf16(
                    crA[a], crB[b], (floatx4){0.f, 0.f, 0.f, 0.f}, 0, 0, 0);
                if (diag) {
#pragma unroll
                    for (int r = 0; r < 4; ++r) {
                        if ((simacc[a][b][r] > 0.8f) && (gRow0 + r != gCol)) {
                            klLocal += cr[r];
                            cntLocal += 1;
                        }
                    }
                } else {
#pragma unroll
                    for (int r = 0; r < 4; ++r) {
                        if (simacc[a][b][r] > 0.8f) {
                            klLocal += cr[r];
                            cntLocal += 2;
                        }
                    }
                }
            }
        }

        prev_bi = bi;
        bi = nbi;
        bj = nbj;
    }

    klLocal = wredf(klLocal);
    cntLocal = wredi(cntLocal);

    __syncthreads();
    float* redk = (float*)&sh[0][0][0];
    int* redc = (int*)(redk + 8);
    if (lane == 0) { redk[wave] = klLocal; redc[wave] = cntLocal; }
    __syncthreads();

    if (t == 0) {
        float k = 0.f;
        int c = 0;
#pragma unroll
        for (int w = 0; w < 8; ++w) { k += redk[w]; c += redc[w]; }
        klslot[blockIdx.x] = k;                    // unique slot: no atomic
        cntslot[blockIdx.x] = (unsigned int)c;
    }
}

// ---------------- finalize (1 block x 256) ----------------
__global__ void finalize_k(const float* __restrict__ klslot,
                           const unsigned int* __restrict__ cntslot,
                           const float* __restrict__ prepslot,
                           const float* __restrict__ temp,
                           float* __restrict__ out) {
    __shared__ float sk[4];
    __shared__ int sc[4];
    __shared__ float sp[11];
    const int t = threadIdx.x, lane = t & 63, wave = t >> 6;

    float k = 0.f;
    int c = 0;
    for (int i = t; i < NCHUNK; i += 256) { k += klslot[i]; c += (int)cntslot[i]; }
    k = wredf(k);
    c = wredi(c);
    if (lane == 0) { sk[wave] = k; sc[wave] = c; }
    if (t < 11) {
        float s = 0.f;
        for (int r = 0; r < 32; ++r) s += prepslot[r * 11 + t];
        sp[t] = s;
    }
    __syncthreads();
    if (t == 0) {
        float K = sk[0] + sk[1] + sk[2] + sk[3];
        int C = sc[0] + sc[1] + sc[2] + sc[3];
        const float invB = 1.f / (float)B_SZ;
        float task = sp[0] * invB;
        float eff = 0.05f * sp[1] * invB;
        float entl = 0.01f * sp[2] * invB;
        float cons = 0.1f * (C > 0 ? K / (float)C : 0.f);
        float u[8], mean = 0.f;
        for (int e = 0; e < 8; ++e) { u[e] = sp[3 + e] * invB; mean += u[e]; }
        mean *= 0.125f;
        float var = 0.f;
        for (int e = 0; e < 8; ++e) { float d = u[e] - mean; var += d * d; }
        var *= (1.f / 7.f);                // unbiased (ddof=1)
        float lb = 0.1f * var * 64.f;      // * E^2
        float tt = temp[0] - 1.f;
        out[0] = task + lb + eff + cons + entl + 0.01f * tt * tt;
    }
}

// ---------------- launch ----------------
extern "C" void kernel_launch(void* const* d_in, const int* in_sizes, int n_in,
                              void* d_out, int out_size, void* d_ws, size_t ws_size,
                              hipStream_t stream) {
    const float* logits = (const float*)d_in[0];
    const int* targets = (const int*)d_in[1];
    const float* routing = (const float*)d_in[2];
    const float* emb = (const float*)d_in[3];
    const float* temp = (const float*)d_in[4];

    char* ws = (char*)d_ws;
    unsigned short* nrm = (unsigned short*)ws;
    unsigned short* nlq = (unsigned short*)(ws + 2097152);
    unsigned short* pb = (unsigned short*)(ws + 2228224);
    float* aprime = (float*)(ws + 2359296);
    float* klslot = (float*)(ws + 2392064);
    unsigned int* cntslot = (unsigned int*)(ws + 2394144);
    float* prepslot = (float*)(ws + 2396224);

    prep_all<<<2080, 256, 0, stream>>>(logits, targets, routing, emb,
                                       nrm, nlq, pb, aprime, prepslot);
    tile_sym<<<NCHUNK, 512, 0, stream>>>(nrm, nlq, pb, aprime, klslot, cntslot);
    finalize_k<<<1, 256, 0, stream>>>(klslot, cntslot, prepslot, temp,
                                      (float*)d_out);
}

// Round 6
// 103.182 us; speedup vs baseline: 1.1786x; 1.1786x over previous
//
#include <hip/hip_runtime.h>
#include <stdint.h>

// ---------------- problem constants ----------------
#define B_SZ 8192
#define LOG8 2.0794415416798357f   // -log(1/8)
#define NTILE 2080                 // 64*65/2 upper-triangular 128x128 tiles

typedef __attribute__((ext_vector_type(8))) short short8;
typedef __attribute__((ext_vector_type(4))) float floatx4;

__device__ inline unsigned short f2bf(float f) {
    unsigned int u = __float_as_uint(f);
    u = (u + 0x7FFFu + ((u >> 16) & 1u)) >> 16;   // RNE
    return (unsigned short)u;
}
__device__ inline float bf2f(unsigned short s) {
    return __uint_as_float(((unsigned int)s) << 16);
}
__device__ inline float wredf(float x) {
#pragma unroll
    for (int o = 32; o; o >>= 1) x += __shfl_down(x, o);
    return x;
}
__device__ inline int wredi(int x) {
#pragma unroll
    for (int o = 32; o; o >>= 1) x += __shfl_down(x, o);
    return x;
}

// ws layout:
//  nrm      bf16[8192*128]   @ 0        (2097152 B)
//  nlq      bf16[8192*8]     @ 2097152  (-(logp+log8), sign-flipped bf16)
//  pb       bf16[8192*8]     @ 2228224
//  aprime   f32[8192]        @ 2359296
//  klslot   f32[2080]        @ 2392064  (per-block, non-atomic)
//  cntslot  u32[2080]        @ 2400384
//  prepslot f32[16*11]       @ 2408704

// ---------------- fused prep (272 blocks x 512) ----------------
// blocks 0..255: embeddings, 8 waves x 4 row-iterations = 32 rows/block
// blocks 256..271: routing prep, 512 rows/block
__global__ __launch_bounds__(512) void prep_all(
    const float* __restrict__ logits,
    const int* __restrict__ targets,
    const float* __restrict__ routing,
    const float* __restrict__ emb,
    unsigned short* __restrict__ nrm,
    unsigned short* __restrict__ nlq,
    unsigned short* __restrict__ pb,
    float* __restrict__ aprime,
    float* __restrict__ prepslot) {
    __shared__ float pred[8][11];
    const int bid = blockIdx.x;
    const int lane = threadIdx.x & 63;
    const int wave = threadIdx.x >> 6;

    if (bid < 256) {
        // ---- embedding normalize -> bf16 (wave per row, 4 rows per wave) ----
#pragma unroll
        for (int iter = 0; iter < 4; ++iter) {
            int row = (((iter << 8) + bid) << 3) + wave;
            const float2* e2 = (const float2*)(emb + (size_t)row * 128);
            float2 v = e2[lane];
            float ss = v.x * v.x + v.y * v.y;
            ss = wredf(ss);
            ss = __shfl(ss, 0);
            float inv = rsqrtf(ss);
            ushort2 o;
            o.x = f2bf(v.x * inv);
            o.y = f2bf(v.y * inv);
            ((ushort2*)(nrm + (size_t)row * 128))[lane] = o;
        }
        return;
    }

    // ---- per-row routing prep ----
    int row = ((bid - 256) << 9) + threadIdx.x;

    const float4* r4 = (const float4*)(routing + (size_t)row * 8);
    float4 va = r4[0], vb = r4[1];
    float v[8] = {va.x, va.y, va.z, va.w, vb.x, vb.y, vb.z, vb.w};

    float mx = v[0];
#pragma unroll
    for (int e = 1; e < 8; ++e) mx = fmaxf(mx, v[e]);
    float ex[8], s = 0.f;
#pragma unroll
    for (int e = 0; e < 8; ++e) { ex[e] = expf(v[e] - mx); s += ex[e]; }
    float ls = logf(s);
    float inv_s = 1.f / s;

    union { unsigned short u[8]; uint4 q; } lu, pu;
    float ap = 0.f;
#pragma unroll
    for (int e = 0; e < 8; ++e) {
        unsigned short pe = f2bf(ex[e] * inv_s);
        unsigned short le = f2bf(v[e] - mx - ls + LOG8);
        pu.u[e] = pe;
        lu.u[e] = le ^ 0x8000;             // store -lq (exact sign flip)
        ap += bf2f(pe) * bf2f(le);
    }
    ((uint4*)nlq)[row] = lu.q;
    ((uint4*)pb)[row] = pu.q;
    aprime[row] = ap;

    float eff = 0.f, ent = 0.f;
#pragma unroll
    for (int e = 0; e < 8; ++e) {
        if (v[e] < 0.1f) eff += v[e];
        ent += v[e] * logf(v[e] + 1e-8f);
    }

    const float* lg = logits + (size_t)row * 3;
    float a0 = lg[0], a1 = lg[1], a2 = lg[2];
    float mm = fmaxf(a0, fmaxf(a1, a2));
    float lse = mm + logf(expf(a0 - mm) + expf(a1 - mm) + expf(a2 - mm));
    int tg = targets[row];
    float tv = (tg == 0) ? a0 : ((tg == 1) ? a1 : a2);
    float task = lse - tv;

    task = wredf(task);
    eff = wredf(eff);
    ent = wredf(ent);
    float cs[8];
#pragma unroll
    for (int e = 0; e < 8; ++e) cs[e] = wredf(v[e]);

    if (lane == 0) {
        pred[wave][0] = task;
        pred[wave][1] = eff;
        pred[wave][2] = ent;
#pragma unroll
        for (int e = 0; e < 8; ++e) pred[wave][3 + e] = cs[e];
    }
    __syncthreads();
    if (threadIdx.x < 11) {
        float s2 = 0.f;
#pragma unroll
        for (int w = 0; w < 8; ++w) s2 += pred[w][threadIdx.x];
        prepslot[(bid - 256) * 11 + threadIdx.x] = s2;
    }
}

// ---------------- main: symmetric fused sim-mask + KL ----------------
// upper-triangular 128x128 tiles; 512 threads (8 waves in 2x4); XOR-swizzled LDS
__global__ __launch_bounds__(512, 4) void tile_sym(
    const unsigned short* __restrict__ nrm,
    const unsigned short* __restrict__ nlq,
    const unsigned short* __restrict__ pb,
    const float* __restrict__ aprime,
    float* __restrict__ klslot,
    unsigned int* __restrict__ cntslot) {
    __shared__ uint4 sh[2][128][16];   // 64 KB

    const int t = threadIdx.x;
    const int L = blockIdx.x;

    // triangular decode: bi <= bj
    int bi = (int)((129.0f - sqrtf((float)(16641 - 8 * L))) * 0.5f);
    int T = bi * 64 - ((bi * (bi - 1)) >> 1);
    while (L < T) { --bi; T = bi * 64 - ((bi * (bi - 1)) >> 1); }
    while (L >= T + (64 - bi)) { T += 64 - bi; ++bi; }
    const int bj = bi + (L - T);
    const bool diag = (bi == bj);
    const int iBase = bi << 7, jBase = bj << 7;

    // stage A and B unconditionally
    const uint4* n4 = (const uint4*)nrm;
#pragma unroll
    for (int it = 0; it < 4; ++it) {
        int c = t + (it << 9);
        int row = c >> 4, g = c & 15;
        int gp = g ^ (row & 15);
        uint4 va = n4[((size_t)(iBase + row) << 4) + g];
        uint4 vb = n4[((size_t)(jBase + row) << 4) + g];
        sh[0][row][gp] = va;
        sh[1][row][gp] = vb;
    }

    const int wave = t >> 6, lane = t & 63;
    const int wr = wave >> 2, wc = wave & 3;   // 2 x 4 wave grid
    const int m = lane & 15, q = lane >> 4;
    const short8 zero8 = (short8){0, 0, 0, 0, 0, 0, 0, 0};

    // cross fragments: kl[i,j](+kl[j,i]) = ap_i + ap_j - lq_i.p_j - p_i.lq_j
    //  A: q0 = -lq_i, q1 = p_i (0 on diag), q2: k16=bf16(ap_i)(0 on diag), k17=1
    //  B: q0 = p_j,   q1 = -lq_j,           q2: k16=1, k17=bf16(ap_j)
    short8 crA[4], crB[2];
#pragma unroll
    for (int a = 0; a < 4; ++a) {
        int ri = iBase + (wr << 6) + (a << 4) + m;
        short8 v = zero8;
        if (q == 0) v = *(const short8*)&nlq[(size_t)ri << 3];
        else if (q == 1) { if (!diag) v = *(const short8*)&pb[(size_t)ri << 3]; }
        else if (q == 2) {
            v[1] = (short)0x3F80;
            if (!diag) v[0] = (short)f2bf(aprime[ri]);
        }
        crA[a] = v;
    }
#pragma unroll
    for (int b = 0; b < 2; ++b) {
        int cj = jBase + (wc << 5) + (b << 4) + m;
        short8 v = zero8;
        if (q == 0) v = *(const short8*)&pb[(size_t)cj << 3];
        else if (q == 1) v = *(const short8*)&nlq[(size_t)cj << 3];
        else if (q == 2) {
            v[0] = (short)0x3F80;
            v[1] = (short)f2bf(aprime[cj]);
        }
        crB[b] = v;
    }

    __syncthreads();

    const unsigned short* Ab = (const unsigned short*)&sh[0][0][0];
    const unsigned short* Bb = (const unsigned short*)&sh[1][0][0];

    floatx4 simacc[4][2];
#pragma unroll
    for (int a = 0; a < 4; ++a)
#pragma unroll
        for (int b = 0; b < 2; ++b) simacc[a][b] = (floatx4){0.f, 0.f, 0.f, 0.f};

    // sim = A . B^T over K=128
#pragma unroll
    for (int ks = 0; ks < 4; ++ks) {
        const int g = (ks << 2) + q;
        short8 af[4], bfr[2];
#pragma unroll
        for (int a = 0; a < 4; ++a) {
            int ra = (wr << 6) + (a << 4) + m;
            af[a] = *(const short8*)&Ab[(ra << 7) + ((g ^ m) << 3)];
        }
#pragma unroll
        for (int b = 0; b < 2; ++b) {
            int rb = (wc << 5) + (b << 4) + m;
            bfr[b] = *(const short8*)&Bb[(rb << 7) + ((g ^ m) << 3)];
        }
#pragma unroll
        for (int a = 0; a < 4; ++a)
#pragma unroll
            for (int b = 0; b < 2; ++b)
                simacc[a][b] = __builtin_amdgcn_mfma_f32_16x16x32_bf16(
                    af[a], bfr[b], simacc[a][b], 0, 0, 0);
    }

    // epilogue: kl via one MFMA, then masked accumulate
    float klLocal = 0.f;
    int cntLocal = 0;
#pragma unroll
    for (int a = 0; a < 4; ++a) {
        const int gRow0 = iBase + (wr << 6) + (a << 4) + (q << 2);
#pragma unroll
        for (int b = 0; b < 2; ++b) {
            const int gCol = jBase + (wc << 5) + (b << 4) + m;
            floatx4 cr = __builtin_amdgcn_mfma_f32_16x16x32_bf16(
                crA[a], crB[b], (floatx4){0.f, 0.f, 0.f, 0.f}, 0, 0, 0);
            if (diag) {
#pragma unroll
                for (int r = 0; r < 4; ++r) {
                    if ((simacc[a][b][r] > 0.8f) && (gRow0 + r != gCol)) {
                        klLocal += cr[r];
                        cntLocal += 1;
                    }
                }
            } else {
#pragma unroll
                for (int r = 0; r < 4; ++r) {
                    if (simacc[a][b][r] > 0.8f) {
                        klLocal += cr[r];
                        cntLocal += 2;
                    }
                }
            }
        }
    }

    klLocal = wredf(klLocal);
    cntLocal = wredi(cntLocal);

    __syncthreads();
    float* redk = (float*)&sh[0][0][0];
    int* redc = (int*)(redk + 8);
    if (lane == 0) { redk[wave] = klLocal; redc[wave] = cntLocal; }
    __syncthreads();

    if (t == 0) {
        float k = 0.f;
        int c = 0;
#pragma unroll
        for (int w = 0; w < 8; ++w) { k += redk[w]; c += redc[w]; }
        klslot[L] = k;                     // unique slot: no atomic
        cntslot[L] = (unsigned int)c;
    }
}

// ---------------- finalize (1 block x 256) ----------------
__global__ void finalize_k(const float* __restrict__ klslot,
                           const unsigned int* __restrict__ cntslot,
                           const float* __restrict__ prepslot,
                           const float* __restrict__ temp,
                           float* __restrict__ out) {
    __shared__ float sk[4];
    __shared__ int sc[4];
    __shared__ float sp[11];
    const int t = threadIdx.x, lane = t & 63, wave = t >> 6;

    float k = 0.f;
    int c = 0;
    for (int i = t; i < NTILE; i += 256) { k += klslot[i]; c += (int)cntslot[i]; }
    k = wredf(k);
    c = wredi(c);
    if (lane == 0) { sk[wave] = k; sc[wave] = c; }
    if (t < 11) {
        float s = 0.f;
        for (int r = 0; r < 16; ++r) s += prepslot[r * 11 + t];
        sp[t] = s;
    }
    __syncthreads();
    if (t == 0) {
        float K = sk[0] + sk[1] + sk[2] + sk[3];
        int C = sc[0] + sc[1] + sc[2] + sc[3];
        const float invB = 1.f / (float)B_SZ;
        float task = sp[0] * invB;
        float eff = 0.05f * sp[1] * invB;
        float entl = 0.01f * sp[2] * invB;
        float cons = 0.1f * (C > 0 ? K / (float)C : 0.f);
        float u[8], mean = 0.f;
        for (int e = 0; e < 8; ++e) { u[e] = sp[3 + e] * invB; mean += u[e]; }
        mean *= 0.125f;
        float var = 0.f;
        for (int e = 0; e < 8; ++e) { float d = u[e] - mean; var += d * d; }
        var *= (1.f / 7.f);                // unbiased (ddof=1)
        float lb = 0.1f * var * 64.f;      // * E^2
        float tt = temp[0] - 1.f;
        out[0] = task + lb + eff + cons + entl + 0.01f * tt * tt;
    }
}

// ---------------- launch ----------------
extern "C" void kernel_launch(void* const* d_in, const int* in_sizes, int n_in,
                              void* d_out, int out_size, void* d_ws, size_t ws_size,
                              hipStream_t stream) {
    const float* logits = (const float*)d_in[0];
    const int* targets = (const int*)d_in[1];
    const float* routing = (const float*)d_in[2];
    const float* emb = (const float*)d_in[3];
    const float* temp = (const float*)d_in[4];

    char* ws = (char*)d_ws;
    unsigned short* nrm = (unsigned short*)ws;
    unsigned short* nlq = (unsigned short*)(ws + 2097152);
    unsigned short* pb = (unsigned short*)(ws + 2228224);
    float* aprime = (float*)(ws + 2359296);
    float* klslot = (float*)(ws + 2392064);
    unsigned int* cntslot = (unsigned int*)(ws + 2400384);
    float* prepslot = (float*)(ws + 2408704);

    prep_all<<<272, 512, 0, stream>>>(logits, targets, routing, emb,
                                      nrm, nlq, pb, aprime, prepslot);
    tile_sym<<<NTILE, 512, 0, stream>>>(nrm, nlq, pb, aprime, klslot, cntslot);
    finalize_k<<<1, 256, 0, stream>>>(klslot, cntslot, prepslot, temp,
                                      (float*)d_out);
}

// Round 7
// 101.922 us; speedup vs baseline: 1.1932x; 1.0124x over previous
//
#include <hip/hip_runtime.h>
#include <stdint.h>

// ---------------- problem constants ----------------
#define B_SZ 8192
#define LOG8 2.0794415416798357f   // -log(1/8)
#define NTILE 2080                 // 64*65/2 upper-triangular 128x128 tiles

typedef __attribute__((ext_vector_type(8))) short short8;
typedef __attribute__((ext_vector_type(4))) float floatx4;

typedef __attribute__((address_space(1))) const uint4 guint4;
typedef __attribute__((address_space(3))) uint4 luint4;

// async global->LDS 16B copy: per-lane global addr, wave-uniform LDS base,
// HW scatters lane l to base + l*16.
__device__ inline void async_cp16(const uint4* g, uint4* l) {
    __builtin_amdgcn_global_load_lds((guint4*)g, (luint4*)l, 16, 0, 0);
}

__device__ inline unsigned short f2bf(float f) {
    unsigned int u = __float_as_uint(f);
    u = (u + 0x7FFFu + ((u >> 16) & 1u)) >> 16;   // RNE
    return (unsigned short)u;
}
__device__ inline float bf2f(unsigned short s) {
    return __uint_as_float(((unsigned int)s) << 16);
}
__device__ inline float wredf(float x) {
#pragma unroll
    for (int o = 32; o; o >>= 1) x += __shfl_down(x, o);
    return x;
}
__device__ inline int wredi(int x) {
#pragma unroll
    for (int o = 32; o; o >>= 1) x += __shfl_down(x, o);
    return x;
}

// ws layout:
//  nrm      bf16[8192*128]   @ 0        (2097152 B)
//  nlq      bf16[8192*8]     @ 2097152  (-(logp+log8), sign-flipped bf16)
//  pb       bf16[8192*8]     @ 2228224
//  aprime   f32[8192]        @ 2359296
//  klslot   f32[2080]        @ 2392064  (per-block, non-atomic)
//  cntslot  u32[2080]        @ 2400384
//  prepslot f32[16*11]       @ 2408704

// ---------------- fused prep (272 blocks x 512) ----------------
__global__ __launch_bounds__(512) void prep_all(
    const float* __restrict__ logits,
    const int* __restrict__ targets,
    const float* __restrict__ routing,
    const float* __restrict__ emb,
    unsigned short* __restrict__ nrm,
    unsigned short* __restrict__ nlq,
    unsigned short* __restrict__ pb,
    float* __restrict__ aprime,
    float* __restrict__ prepslot) {
    __shared__ float pred[8][11];
    const int bid = blockIdx.x;
    const int lane = threadIdx.x & 63;
    const int wave = threadIdx.x >> 6;

    if (bid < 256) {
#pragma unroll
        for (int iter = 0; iter < 4; ++iter) {
            int row = (((iter << 8) + bid) << 3) + wave;
            const float2* e2 = (const float2*)(emb + (size_t)row * 128);
            float2 v = e2[lane];
            float ss = v.x * v.x + v.y * v.y;
            ss = wredf(ss);
            ss = __shfl(ss, 0);
            float inv = rsqrtf(ss);
            ushort2 o;
            o.x = f2bf(v.x * inv);
            o.y = f2bf(v.y * inv);
            ((ushort2*)(nrm + (size_t)row * 128))[lane] = o;
        }
        return;
    }

    int row = ((bid - 256) << 9) + threadIdx.x;

    const float4* r4 = (const float4*)(routing + (size_t)row * 8);
    float4 va = r4[0], vb = r4[1];
    float v[8] = {va.x, va.y, va.z, va.w, vb.x, vb.y, vb.z, vb.w};

    float mx = v[0];
#pragma unroll
    for (int e = 1; e < 8; ++e) mx = fmaxf(mx, v[e]);
    float ex[8], s = 0.f;
#pragma unroll
    for (int e = 0; e < 8; ++e) { ex[e] = expf(v[e] - mx); s += ex[e]; }
    float ls = logf(s);
    float inv_s = 1.f / s;

    union { unsigned short u[8]; uint4 q; } lu, pu;
    float ap = 0.f;
#pragma unroll
    for (int e = 0; e < 8; ++e) {
        unsigned short pe = f2bf(ex[e] * inv_s);
        unsigned short le = f2bf(v[e] - mx - ls + LOG8);
        pu.u[e] = pe;
        lu.u[e] = le ^ 0x8000;             // store -lq (exact sign flip)
        ap += bf2f(pe) * bf2f(le);
    }
    ((uint4*)nlq)[row] = lu.q;
    ((uint4*)pb)[row] = pu.q;
    aprime[row] = ap;

    float eff = 0.f, ent = 0.f;
#pragma unroll
    for (int e = 0; e < 8; ++e) {
        if (v[e] < 0.1f) eff += v[e];
        ent += v[e] * logf(v[e] + 1e-8f);
    }

    const float* lg = logits + (size_t)row * 3;
    float a0 = lg[0], a1 = lg[1], a2 = lg[2];
    float mm = fmaxf(a0, fmaxf(a1, a2));
    float lse = mm + logf(expf(a0 - mm) + expf(a1 - mm) + expf(a2 - mm));
    int tg = targets[row];
    float tv = (tg == 0) ? a0 : ((tg == 1) ? a1 : a2);
    float task = lse - tv;

    task = wredf(task);
    eff = wredf(eff);
    ent = wredf(ent);
    float cs[8];
#pragma unroll
    for (int e = 0; e < 8; ++e) cs[e] = wredf(v[e]);

    if (lane == 0) {
        pred[wave][0] = task;
        pred[wave][1] = eff;
        pred[wave][2] = ent;
#pragma unroll
        for (int e = 0; e < 8; ++e) pred[wave][3 + e] = cs[e];
    }
    __syncthreads();
    if (threadIdx.x < 11) {
        float s2 = 0.f;
#pragma unroll
        for (int w = 0; w < 8; ++w) s2 += pred[w][threadIdx.x];
        prepslot[(bid - 256) * 11 + threadIdx.x] = s2;
    }
}

// ---------------- main: symmetric fused sim-mask + KL ----------------
// 128x128 upper-tri tiles; 512 thr (8 waves 2x4); global_load_lds staging,
// split-K pipeline (chunk1 copies overlap chunk0 compute), XOR on global addr.
// LDS planes (uint4[1024] each): 0=A k0-63, 1=B k0-63, 2=A k64-127, 3=B k64-127
// plane slot (row*8 + s) holds global granule chunk*8 + (s ^ (row&7)).
__global__ __launch_bounds__(512, 4) void tile_sym(
    const unsigned short* __restrict__ nrm,
    const unsigned short* __restrict__ nlq,
    const unsigned short* __restrict__ pb,
    const float* __restrict__ aprime,
    float* __restrict__ klslot,
    unsigned int* __restrict__ cntslot) {
    __shared__ uint4 sh[4096];   // 64 KB

    const int t = threadIdx.x;
    const int L = blockIdx.x;
    const int wave = t >> 6, lane = t & 63;

    // triangular decode: bi <= bj
    int bi = (int)((129.0f - sqrtf((float)(16641 - 8 * L))) * 0.5f);
    int T = bi * 64 - ((bi * (bi - 1)) >> 1);
    while (L < T) { --bi; T = bi * 64 - ((bi * (bi - 1)) >> 1); }
    while (L >= T + (64 - bi)) { T += 64 - bi; ++bi; }
    const int bj = bi + (L - T);
    const bool diag = (bi == bj);
    const int iBase = bi << 7, jBase = bj << 7;

    const uint4* n4 = (const uint4*)nrm;
    const int s0 = t & 7, r0 = t >> 3;            // slot t
    const int s1 = (t + 512) & 7, r1 = (t + 512) >> 3;
    const int g0 = s0 ^ (r0 & 7), g1 = s1 ^ (r1 & 7);

    // ---- issue chunk0 copies (planes 0,1 = k 0..63) ----
    async_cp16(&n4[((size_t)(iBase + r0) << 4) + g0], sh + (wave << 6));
    async_cp16(&n4[((size_t)(iBase + r1) << 4) + g1], sh + 512 + (wave << 6));
    async_cp16(&n4[((size_t)(jBase + r0) << 4) + g0], sh + 1024 + (wave << 6));
    async_cp16(&n4[((size_t)(jBase + r1) << 4) + g1], sh + 1536 + (wave << 6));

    __syncthreads();                   // drains exactly the 4 chunk0 ops

    // ---- issue chunk1 copies (planes 2,3 = k 64..127) ----
    async_cp16(&n4[((size_t)(iBase + r0) << 4) + 8 + g0], sh + 2048 + (wave << 6));
    async_cp16(&n4[((size_t)(iBase + r1) << 4) + 8 + g1], sh + 2560 + (wave << 6));
    async_cp16(&n4[((size_t)(jBase + r0) << 4) + 8 + g0], sh + 3072 + (wave << 6));
    async_cp16(&n4[((size_t)(jBase + r1) << 4) + 8 + g1], sh + 3584 + (wave << 6));

    const int wr = wave >> 2, wc = wave & 3;   // 2 x 4 wave grid
    const int m = lane & 15, q = lane >> 4;
    const short8 zero8 = (short8){0, 0, 0, 0, 0, 0, 0, 0};

    // cross fragments (overlap chunk1 flight):
    //  A: q0 = -lq_i, q1 = p_i (0 on diag), q2: k16=bf16(ap_i)(0 on diag), k17=1
    //  B: q0 = p_j,   q1 = -lq_j,           q2: k16=1, k17=bf16(ap_j)
    short8 crA[4], crB[2];
#pragma unroll
    for (int a = 0; a < 4; ++a) {
        int ri = iBase + (wr << 6) + (a << 4) + m;
        short8 v = zero8;
        if (q == 0) v = *(const short8*)&nlq[(size_t)ri << 3];
        else if (q == 1) { if (!diag) v = *(const short8*)&pb[(size_t)ri << 3]; }
        else if (q == 2) {
            v[1] = (short)0x3F80;
            if (!diag) v[0] = (short)f2bf(aprime[ri]);
        }
        crA[a] = v;
    }
#pragma unroll
    for (int b = 0; b < 2; ++b) {
        int cj = jBase + (wc << 5) + (b << 4) + m;
        short8 v = zero8;
        if (q == 0) v = *(const short8*)&pb[(size_t)cj << 3];
        else if (q == 1) v = *(const short8*)&nlq[(size_t)cj << 3];
        else if (q == 2) {
            v[0] = (short)0x3F80;
            v[1] = (short)f2bf(aprime[cj]);
        }
        crB[b] = v;
    }

    floatx4 simacc[4][2];
#pragma unroll
    for (int a = 0; a < 4; ++a)
#pragma unroll
        for (int b = 0; b < 2; ++b) simacc[a][b] = (floatx4){0.f, 0.f, 0.f, 0.f};

    const int m7 = m & 7;
    const int raOff = (wr << 6) << 3;              // A row base * 8
    const int rbOff = (wc << 5) << 3;              // B row base * 8

    // ---- compute ks=0,1 from planes 0,1 (chunk0 already resident) ----
#pragma unroll
    for (int ks = 0; ks < 2; ++ks) {
        const int sg = ((ks << 2) + q) ^ m7;       // gw ^ (row&7)
        short8 af[4], bfr[2];
#pragma unroll
        for (int a = 0; a < 4; ++a)
            af[a] = *(const short8*)(sh + raOff + (((a << 4) + m) << 3) + sg);
#pragma unroll
        for (int b = 0; b < 2; ++b)
            bfr[b] = *(const short8*)(sh + 1024 + rbOff + (((b << 4) + m) << 3) + sg);
#pragma unroll
        for (int a = 0; a < 4; ++a)
#pragma unroll
            for (int b = 0; b < 2; ++b)
                simacc[a][b] = __builtin_amdgcn_mfma_f32_16x16x32_bf16(
                    af[a], bfr[b], simacc[a][b], 0, 0, 0);
    }

    __syncthreads();                   // drains chunk1 copies

    // ---- compute ks=2,3 from planes 2,3 ----
#pragma unroll
    for (int ks = 0; ks < 2; ++ks) {
        const int sg = ((ks << 2) + q) ^ m7;
        short8 af[4], bfr[2];
#pragma unroll
        for (int a = 0; a < 4; ++a)
            af[a] = *(const short8*)(sh + 2048 + raOff + (((a << 4) + m) << 3) + sg);
#pragma unroll
        for (int b = 0; b < 2; ++b)
            bfr[b] = *(const short8*)(sh + 3072 + rbOff + (((b << 4) + m) << 3) + sg);
#pragma unroll
        for (int a = 0; a < 4; ++a)
#pragma unroll
            for (int b = 0; b < 2; ++b)
                simacc[a][b] = __builtin_amdgcn_mfma_f32_16x16x32_bf16(
                    af[a], bfr[b], simacc[a][b], 0, 0, 0);
    }

    // epilogue: kl via one MFMA, then masked accumulate
    float klLocal = 0.f;
    int cntLocal = 0;
#pragma unroll
    for (int a = 0; a < 4; ++a) {
        const int gRow0 = iBase + (wr << 6) + (a << 4) + (q << 2);
#pragma unroll
        for (int b = 0; b < 2; ++b) {
            const int gCol = jBase + (wc << 5) + (b << 4) + m;
            floatx4 cr = __builtin_amdgcn_mfma_f32_16x16x32_bf16(
                crA[a], crB[b], (floatx4){0.f, 0.f, 0.f, 0.f}, 0, 0, 0);
            if (diag) {
#pragma unroll
                for (int r = 0; r < 4; ++r) {
                    if ((simacc[a][b][r] > 0.8f) && (gRow0 + r != gCol)) {
                        klLocal += cr[r];
                        cntLocal += 1;
                    }
                }
            } else {
#pragma unroll
                for (int r = 0; r < 4; ++r) {
                    if (simacc[a][b][r] > 0.8f) {
                        klLocal += cr[r];
                        cntLocal += 2;
                    }
                }
            }
        }
    }

    klLocal = wredf(klLocal);
    cntLocal = wredi(cntLocal);

    __syncthreads();
    float* redk = (float*)sh;
    int* redc = (int*)(redk + 8);
    if (lane == 0) { redk[wave] = klLocal; redc[wave] = cntLocal; }
    __syncthreads();

    if (t == 0) {
        float k = 0.f;
        int c = 0;
#pragma unroll
        for (int w = 0; w < 8; ++w) { k += redk[w]; c += redc[w]; }
        klslot[L] = k;                     // unique slot: no atomic
        cntslot[L] = (unsigned int)c;
    }
}

// ---------------- finalize (1 block x 256) ----------------
__global__ void finalize_k(const float* __restrict__ klslot,
                           const unsigned int* __restrict__ cntslot,
                           const float* __restrict__ prepslot,
                           const float* __restrict__ temp,
                           float* __restrict__ out) {
    __shared__ float sk[4];
    __shared__ int sc[4];
    __shared__ float sp[11];
    const int t = threadIdx.x, lane = t & 63, wave = t >> 6;

    float k = 0.f;
    int c = 0;
    for (int i = t; i < NTILE; i += 256) { k += klslot[i]; c += (int)cntslot[i]; }
    k = wredf(k);
    c = wredi(c);
    if (lane == 0) { sk[wave] = k; sc[wave] = c; }
    if (t < 11) {
        float s = 0.f;
        for (int r = 0; r < 16; ++r) s += prepslot[r * 11 + t];
        sp[t] = s;
    }
    __syncthreads();
    if (t == 0) {
        float K = sk[0] + sk[1] + sk[2] + sk[3];
        int C = sc[0] + sc[1] + sc[2] + sc[3];
        const float invB = 1.f / (float)B_SZ;
        float task = sp[0] * invB;
        float eff = 0.05f * sp[1] * invB;
        float entl = 0.01f * sp[2] * invB;
        float cons = 0.1f * (C > 0 ? K / (float)C : 0.f);
        float u[8], mean = 0.f;
        for (int e = 0; e < 8; ++e) { u[e] = sp[3 + e] * invB; mean += u[e]; }
        mean *= 0.125f;
        float var = 0.f;
        for (int e = 0; e < 8; ++e) { float d = u[e] - mean; var += d * d; }
        var *= (1.f / 7.f);                // unbiased (ddof=1)
        float lb = 0.1f * var * 64.f;      // * E^2
        float tt = temp[0] - 1.f;
        out[0] = task + lb + eff + cons + entl + 0.01f * tt * tt;
    }
}

// ---------------- launch ----------------
extern "C" void kernel_launch(void* const* d_in, const int* in_sizes, int n_in,
                              void* d_out, int out_size, void* d_ws, size_t ws_size,
                              hipStream_t stream) {
    const float* logits = (const float*)d_in[0];
    const int* targets = (const int*)d_in[1];
    const float* routing = (const float*)d_in[2];
    const float* emb = (const float*)d_in[3];
    const float* temp = (const float*)d_in[4];

    char* ws = (char*)d_ws;
    unsigned short* nrm = (unsigned short*)ws;
    unsigned short* nlq = (unsigned short*)(ws + 2097152);
    unsigned short* pb = (unsigned short*)(ws + 2228224);
    float* aprime = (float*)(ws + 2359296);
    float* klslot = (float*)(ws + 2392064);
    unsigned int* cntslot = (unsigned int*)(ws + 2400384);
    float* prepslot = (float*)(ws + 2408704);

    prep_all<<<272, 512, 0, stream>>>(logits, targets, routing, emb,
                                      nrm, nlq, pb, aprime, prepslot);
    tile_sym<<<NTILE, 512, 0, stream>>>(nrm, nlq, pb, aprime, klslot, cntslot);
    finalize_k<<<1, 256, 0, stream>>>(klslot, cntslot, prepslot, temp,
                                      (float*)d_out);
}